// Round 3
// baseline (56.539 us; speedup 1.0000x reference)
//
#include <hip/hip_runtime.h>

// StraightRenderer: G=512, S=32 strokes x P=8 points -> 224 segments.
// out[i,j] = min(1, min_seg dist((i,j),seg)/(2*t_stroke))
//          = min(1, sqrt(min_seg dist^2 * scale_stroke)), scale = 1/(4t^2).
//
// Output clamps at 1.0 and 2t <= 5 px -> a segment only matters within 2t px.
// 16x16 px tiles (1024 blocks, 4/CU); cull vs tile bounding circle
// (half-diag 10.61 -> margin 11) + 2t; compact survivors into LDS.
// Expected survivors ~7 of 224. Segment record: 2x float4 with e*inv
// prefolded so frac = med3(fma(pvy,fy, pvx*fx)).

#define NSEG 224

__global__ __launch_bounds__(256) void render_kernel(
    const float* __restrict__ strokes,   // [32,8,2] in [0,1]
    const float* __restrict__ thick,     // [32]
    float* __restrict__ out)             // [512,512]
{
    __shared__ float4 sa[NSEG];   // ax, ay, ex, ey        (pixel coords)
    __shared__ float4 sb[NSEG];   // ex*inv, ey*inv, scale, (pad)
    __shared__ int cnt;
    const int tid = threadIdx.x;

    const int tile_j = blockIdx.x & 31;   // 32 tiles across j
    const int tile_i = blockIdx.x >> 5;   // 32 tiles across i
    const int i0 = tile_i << 4;
    const int j0 = tile_j << 4;
    const float ccx = (float)i0 + 7.5f;   // tile center
    const float ccy = (float)j0 + 7.5f;
    // half-diagonal = 7.5*sqrt(2) = 10.61; margin to 11.0

    if (tid == 0) cnt = 0;
    __syncthreads();

    if (tid < NSEG) {
        const int s = tid / 7;
        const int k = tid - s * 7;
        const int base = (s * 8 + k) * 2;
        float ax = strokes[base + 0];
        float ay = strokes[base + 1];
        float bx = strokes[base + 2];
        float by = strokes[base + 3];
        ax = fminf(fmaxf(ax, 0.0f), 1.0f) * 512.0f;
        ay = fminf(fmaxf(ay, 0.0f), 1.0f) * 512.0f;
        bx = fminf(fmaxf(bx, 0.0f), 1.0f) * 512.0f;
        by = fminf(fmaxf(by, 0.0f), 1.0f) * 512.0f;
        const float ex = bx - ax;
        const float ey = by - ay;
        const float d2 = ex * ex + ey * ey;
        const float inv = 1.0f / (d2 + 1e-5f);
        const float t  = fmaxf(thick[s] * 2.0f + 0.5f, 0.5f);
        // cull: distance from tile center to segment vs (2t + 11)
        const float pvx = ccx - ax;
        const float pvy = ccy - ay;
        float f = fmaf(pvy, ey, pvx * ex) * inv;
        f = fminf(fmaxf(f, 0.0f), 1.0f);
        const float dx = fmaf(-f, ex, pvx);
        const float dy = fmaf(-f, ey, pvy);
        const float d2c = fmaf(dy, dy, dx * dx);
        const float thr = 2.0f * t + 11.0f;
        if (d2c < thr * thr) {
            const int idx = atomicAdd(&cnt, 1);   // order-independent (min)
            sa[idx] = make_float4(ax, ay, ex, ey);
            sb[idx] = make_float4(ex * inv, ey * inv, 1.0f / (4.0f * t * t), 0.0f);
        }
    }
    __syncthreads();
    const int n_kept = cnt;

    // 1 pixel per thread: 16 threads/row x 16 rows
    const int pi = i0 + (tid >> 4);
    const int pj = j0 + (tid & 15);
    const float px = (float)pi;
    const float py = (float)pj;

    float acc = 4.0f;   // sqrt(4)=2 -> clamps to 1 if nothing near
    for (int g = 0; g < n_kept; ++g) {
        const float4 A = sa[g];   // broadcast ds_read_b128
        const float4 B = sb[g];
        const float pvx = px - A.x;
        const float pvy = py - A.y;
        float f = fmaf(pvy, B.y, pvx * B.x);        // (pv . e) * inv, prefolded
        f = fminf(fmaxf(f, 0.0f), 1.0f);            // v_med3_f32
        const float dx = fmaf(-f, A.z, pvx);
        const float dy = fmaf(-f, A.w, pvy);
        const float q = fmaf(dy, dy, dx * dx);
        acc = fminf(acc, q * B.z);
    }

    out[(pi << 9) + pj] = fminf(sqrtf(acc), 1.0f);
}

extern "C" void kernel_launch(void* const* d_in, const int* in_sizes, int n_in,
                              void* d_out, int out_size, void* d_ws, size_t ws_size,
                              hipStream_t stream) {
    const float* strokes = (const float*)d_in[0];
    const float* thick   = (const float*)d_in[1];
    float* out = (float*)d_out;
    hipLaunchKernelGGL(render_kernel, dim3(1024), dim3(256), 0, stream,
                       strokes, thick, out);
}